// Round 6
// baseline (5934.503 us; speedup 1.0000x reference)
//
#include <hip/hip_runtime.h>
#include <math.h>

#define NQ 4096
#define NT 16384
#define DD 32
#define COLIDX 0
#define BIGF 1.0e10f
#define INFF __builtin_inff()

typedef unsigned long long u64;

// pass-1 chunking
#define P1_BLOCKS 2048
#define CHUNK_ELEMS 4096              // 16 KB of dist per block-iteration
#define CHUNK_VECS 1024               // float4s per chunk
#define CHUNKS_PER_ROW 4              // 16384 / 4096
#define N_CHUNKS (NQ * CHUNKS_PER_ROW)   // 16384
#define P1_ITERS (N_CHUNKS / P1_BLOCKS)  // 8

// ---------------------------------------------------------------------------
// bool-width helpers (unknown numpy bool storage: u8 vs i32)
// ---------------------------------------------------------------------------
__device__ __forceinline__ int boolat(const void* p, long long idx, int w32) {
    if (w32) return ((const int*)p)[idx] != 0;
    return ((const unsigned char*)p)[idx] != 0;
}

__device__ __forceinline__ int detect_w32(const void* nm, const void* mk,
                                          int tid, int* s_bad) {
    if (tid == 0) *s_bad = 0;
    __syncthreads();
    const unsigned char* nm8 = (const unsigned char*)nm;
    const unsigned char* mk8 = (const unsigned char*)mk;
    int bad = 0;
    for (int b = tid; b < 4096; b += 256)
        if ((int)nm8[b] + (int)mk8[b] != 1) bad = 1;
    if (bad) atomicOr(s_bad, 1);
    __syncthreads();
    return *s_bad ? 1 : 0;
}

// ---------------------------------------------------------------------------
// prep1: 64 blocks x 256 threads — pot8 pack, colmean partials, inmiss clear.
// ---------------------------------------------------------------------------
__global__ __launch_bounds__(256) void prep1_kernel(
    const void* __restrict__ nm, const void* __restrict__ mk,
    const float* __restrict__ fitX,
    int* __restrict__ wflag, float* __restrict__ partial,
    unsigned char* __restrict__ inmiss, unsigned char* __restrict__ pot8)
{
    __shared__ int s_bad;
    __shared__ float sc[256], sm[256];
    const int tid = threadIdx.x;
    const int w32 = detect_w32(nm, mk, tid, &s_bad);
    if (blockIdx.x == 0 && tid == 0) *wflag = w32;

    const int t = blockIdx.x * 256 + tid;          // 0..16383
    pot8[t] = (unsigned char)boolat(nm, (long long)t * DD + COLIDX, w32);

    float cs = 0.0f, ms = 0.0f;
    if (!boolat(mk, (long long)t * DD + COLIDX, w32)) {
        cs = fitX[(long long)t * DD + COLIDX];
        ms = 1.0f;
    }
    sc[tid] = cs; sm[tid] = ms;
    __syncthreads();
#pragma unroll
    for (int s = 128; s > 0; s >>= 1) {
        if (tid < s) { sc[tid] += sc[tid + s]; sm[tid] += sm[tid + s]; }
        __syncthreads();
    }
    if (tid == 0) { partial[blockIdx.x * 2] = sc[0]; partial[blockIdx.x * 2 + 1] = sm[0]; }

    if (t < NQ) inmiss[t] = 0;
}

__global__ __launch_bounds__(256) void prep2_kernel(
    const int* __restrict__ rmi, const float* __restrict__ partial,
    float* __restrict__ cmean, unsigned char* __restrict__ inmiss)
{
    const int tid = threadIdx.x;
    for (int i = tid; i < NQ; i += 256) {
        int r = rmi[i];
        if (r >= 0 && r < NQ) inmiss[r] = 1;
    }
    if (tid == 0) {
        float c = 0.0f, m = 0.0f;
        for (int b = 0; b < 64; ++b) { c += partial[2 * b]; m += partial[2 * b + 1]; }
        *cmean = c / (m > 0.0f ? m : 1.0f);
    }
}

// ---------------------------------------------------------------------------
// packed-u64 top-5 primitives. key64 = (float_bits << 32) | col.
// Positive-float bit order == numeric order, so u64 asc == (key asc, col asc)
// == exact jax.lax.top_k tie-break, independent of processing order.
// ---------------------------------------------------------------------------
__device__ __forceinline__ u64 packkey(float key, unsigned col) {
    return ((u64)__float_as_uint(key) << 32) | (u64)col;
}

// v[] kept sorted ascending; all indices compile-time.
__device__ __forceinline__ void insert64(u64 k, u64 v[5]) {
    const bool c0 = k < v[0];
    const bool c1 = k < v[1];
    const bool c2 = k < v[2];
    const bool c3 = k < v[3];
    const bool c4 = k < v[4];
    v[4] = c4 ? (c3 ? v[3] : k) : v[4];
    v[3] = c3 ? (c2 ? v[2] : k) : v[3];
    v[2] = c2 ? (c1 ? v[1] : k) : v[2];
    v[1] = c1 ? (c0 ? v[0] : k) : v[1];
    v[0] = c0 ? k : v[0];
}

__device__ __forceinline__ u64 u64min(u64 a, u64 b) { return (b < a) ? b : a; }

__device__ __forceinline__ void cas64(u64& x, u64& y) {
    const bool c = y < x;
    const u64 lo = c ? y : x;
    const u64 hi = c ? x : y;
    x = lo; y = hi;
}

// Merge two ascending sorted-5 lists, keep lowest 5, output sorted.
// Step 1 (half-cleaner of concat(a, reverse(b))): m_i = min(a_i, b_{4-i})
//   -> m holds the 5 smallest of the union and is a MOUNTAIN (asc-then-desc).
// Step 2: sort the mountain. Derivation: prepend three -inf pads -> the
//   8-seq [-inf,-inf,-inf,m0..m4] is asc-then-desc bitonic; run the standard
//   length-8 bitonic merge (distances 4,2,1) and drop pad-comparators:
//   d=4: cas(m0,m4)   (pads absorb the rest)
//   d=2: cas(m1,m3), cas(m2,m4)
//   d=1: cas(m1,m2), cas(m3,m4)
// Hand-verified on [1,5,4,3,2], [5,4,3,2,1], [2,4,5,3,1], [3,6,7,5,2],
// [4,6,3,2,1], and ascending identity.
__device__ __forceinline__ void merge_sorted5(u64 a[5], const u64 b[5]) {
    u64 m0 = u64min(a[0], b[4]);
    u64 m1 = u64min(a[1], b[3]);
    u64 m2 = u64min(a[2], b[2]);
    u64 m3 = u64min(a[3], b[1]);
    u64 m4 = u64min(a[4], b[0]);
    cas64(m0, m4);
    cas64(m1, m3); cas64(m2, m4);
    cas64(m1, m2); cas64(m3, m4);
    a[0] = m0; a[1] = m1; a[2] = m2; a[3] = m3; a[4] = m4;
}

__device__ __forceinline__ u64 shflx64(u64 x, int mask) {
    const int lo = __shfl_xor((int)(unsigned)x, mask, 64);
    const int hi = __shfl_xor((int)(unsigned)(x >> 32), mask, 64);
    return ((u64)(unsigned)hi << 32) | (u64)(unsigned)lo;
}

// ---------------------------------------------------------------------------
// Pass 1: flat contiguous sweep of dist. Block b, iter it -> chunk
// (it*P1_BLOCKS + b) = a 16 KB quarter-row. Instantaneous chip footprint is
// a dense contiguous ~32 MB slab (copy-benchmark pattern) -> DRAM row-hit
// friendly, unlike per-row-per-block streaming (2048 scattered windows).
// Emits per-chunk sorted top-5 (u64) to wslists[chunk][5].
// ---------------------------------------------------------------------------
__global__ __launch_bounds__(256, 6) void pass1_kernel(
    const float* __restrict__ dist,
    const unsigned char* __restrict__ pot8,
    u64* __restrict__ wslists)
{
    __shared__ u64 sv[3][5];
    const int tid = threadIdx.x;
    const int bid = blockIdx.x;
    const float4* dvec = (const float4*)dist;
    const uchar4* pvec = (const uchar4*)pot8;

    // prologue: load chunk for it=0
    long long vb = (long long)bid * CHUNK_VECS;
    float4 c0 = dvec[vb + 0 * 256 + tid];
    float4 c1 = dvec[vb + 1 * 256 + tid];
    float4 c2 = dvec[vb + 2 * 256 + tid];
    float4 c3 = dvec[vb + 3 * 256 + tid];

#pragma unroll 1
    for (int it = 0; it < P1_ITERS; ++it) {
        const int chunkid = it * P1_BLOCKS + bid;

        // prefetch next chunk (contiguous sweep continues)
        float4 n0 = c0, n1 = c1, n2 = c2, n3 = c3;
        if (it + 1 < P1_ITERS) {
            const long long nb = (long long)(chunkid + P1_BLOCKS) * CHUNK_VECS;
            n0 = dvec[nb + 0 * 256 + tid];
            n1 = dvec[nb + 1 * 256 + tid];
            n2 = dvec[nb + 2 * 256 + tid];
            n3 = dvec[nb + 3 * 256 + tid];
        }

        const int sub = chunkid & (CHUNKS_PER_ROW - 1);
        const int pb = sub * 1024;         // uchar4 index base within row
        const uchar4 q0 = pvec[pb + 0 * 256 + tid];
        const uchar4 q1 = pvec[pb + 1 * 256 + tid];
        const uchar4 q2 = pvec[pb + 2 * 256 + tid];
        const uchar4 q3 = pvec[pb + 3 * 256 + tid];

        u64 v[5];
#pragma unroll
        for (int k = 0; k < 5; ++k) v[k] = 0xFFFFFFFFFFFFFFFFULL;

        // key: pot ? (NaN ? BIGF : d) : +inf.  fminf(NaN, BIGF) == BIGF.
#define PROC1(dc, qc, kk)                                                     \
        {                                                                     \
            const unsigned cb = (unsigned)(sub * CHUNK_ELEMS + ((kk)*256 + tid) * 4); \
            { const float key = (qc.x != 0) ? fminf(dc.x, BIGF) : INFF;       \
              insert64(packkey(key, cb + 0), v); }                            \
            { const float key = (qc.y != 0) ? fminf(dc.y, BIGF) : INFF;       \
              insert64(packkey(key, cb + 1), v); }                            \
            { const float key = (qc.z != 0) ? fminf(dc.z, BIGF) : INFF;       \
              insert64(packkey(key, cb + 2), v); }                            \
            { const float key = (qc.w != 0) ? fminf(dc.w, BIGF) : INFF;       \
              insert64(packkey(key, cb + 3), v); }                            \
        }
        PROC1(c0, q0, 0)
        PROC1(c1, q1, 1)
        PROC1(c2, q2, 2)
        PROC1(c3, q3, 3)
#undef PROC1

        // wave butterfly: sorted-list merges; all lanes converge
#pragma unroll
        for (int mask = 1; mask <= 32; mask <<= 1) {
            u64 b[5];
#pragma unroll
            for (int k = 0; k < 5; ++k) b[k] = shflx64(v[k], mask);
            merge_sorted5(v, b);
        }

        const int wave = tid >> 6;
        if (wave > 0 && (tid & 63) == 0) {
#pragma unroll
            for (int k = 0; k < 5; ++k) sv[wave - 1][k] = v[k];
        }
        __syncthreads();
        if (wave == 0) {
            u64 b[5];
#pragma unroll
            for (int w = 0; w < 3; ++w) {
                b[0] = sv[w][0]; b[1] = sv[w][1]; b[2] = sv[w][2];
                b[3] = sv[w][3]; b[4] = sv[w][4];
                merge_sorted5(v, b);
            }
            if (tid == 0) {
#pragma unroll
                for (int k = 0; k < 5; ++k)
                    wslists[(long long)chunkid * 5 + k] = v[k];
            }
        }
        __syncthreads();   // sv reused next iteration

        c0 = n0; c1 = n1; c2 = n2; c3 = n3;
    }
}

// ---------------------------------------------------------------------------
// Pass 2: one thread per query row — merge 4 chunk-lists, epilogue, row copy.
// ---------------------------------------------------------------------------
__global__ __launch_bounds__(256) void pass2_kernel(
    const float* __restrict__ X,
    const u64* __restrict__ wslists,
    const void* __restrict__ maskp,
    const void* __restrict__ mkfitp,
    const float* __restrict__ fitX,
    const int* __restrict__ dmap,
    const int* __restrict__ wflagp,
    const float* __restrict__ cmeanp,
    const unsigned char* __restrict__ inmiss,
    const unsigned char* __restrict__ pot8,
    float* __restrict__ out)
{
    const int r = blockIdx.x * 256 + threadIdx.x;
    if (r >= NQ) return;

    // pass-through copy (cols 1..31); col 0 written below
#pragma unroll
    for (int c = 1; c < DD; ++c)
        out[(long long)r * DD + c] = X[(long long)r * DD + c];

    const int q = dmap[r];
    u64 v[5];
#pragma unroll
    for (int k = 0; k < 5; ++k) v[k] = 0xFFFFFFFFFFFFFFFFULL;
    const u64* lp = wslists + (long long)q * CHUNKS_PER_ROW * 5;
#pragma unroll
    for (int c = 0; c < CHUNKS_PER_ROW * 5; ++c) insert64(lp[c], v);

    const int w32 = *wflagp;
    const bool has_valid = (unsigned)(v[0] >> 32) < __float_as_uint(BIGF);
    const bool receiver =
        inmiss[r] && boolat(maskp, (long long)r * DD + COLIDX, w32);

    float val;
    if (!receiver) {
        val = X[(long long)r * DD + COLIDX];
    } else if (!has_valid) {
        val = *cmeanp;
    } else {
        float keyf[5]; bool ok[5]; int idxc[5];
#pragma unroll
        for (int k = 0; k < 5; ++k) {
            keyf[k] = __uint_as_float((unsigned)(v[k] >> 32));
            const unsigned id = (unsigned)(v[k] & 0xFFFFFFFFu);
            ok[k] = id < NT;
            idxc[k] = ok[k] ? (int)id : 0;
        }
        float dnr[5]; int mfv[5]; unsigned char vldb[5];
#pragma unroll
        for (int k = 0; k < 5; ++k)
            dnr[k] = fitX[(long long)idxc[k] * DD + COLIDX];
#pragma unroll
        for (int k = 0; k < 5; ++k)
            mfv[k] = boolat(mkfitp, (long long)idxc[k] * DD + COLIDX, w32);
#pragma unroll
        for (int k = 0; k < 5; ++k) vldb[k] = pot8[idxc[k]];

        float wk[5];
        bool infrow = false;
#pragma unroll
        for (int k = 0; k < 5; ++k) {
            const float dpot = (keyf[k] == BIGF) ? __builtin_nanf("") : keyf[k];
            const float t = 1.0f / dpot;       // 0->inf, inf->0, NaN->NaN
            wk[k] = ok[k] ? t : 0.0f;
            if (ok[k] && isinf(t)) infrow = true;
        }
        if (infrow) {
#pragma unroll
            for (int k = 0; k < 5; ++k) wk[k] = isinf(wk[k]) ? 1.0f : 0.0f;
        }
#pragma unroll
        for (int k = 0; k < 5; ++k) if (wk[k] != wk[k]) wk[k] = 0.0f;

        float wsum = 0.0f, vsum = 0.0f;
#pragma unroll
        for (int k = 0; k < 5; ++k) {
            const float dm = ok[k] ? (1.0f - (float)mfv[k]) : 0.0f;
            const float vl = ok[k] ? (float)vldb[k] : 0.0f;
            const float nw = dm * wk[k] * vl;
            wsum += nw;
            vsum += dnr[k] * nw;
        }
        const float div = (wsum == 0.0f) ? 1.0f : wsum;
        val = vsum / div;
    }
    out[(long long)r * DD + COLIDX] = val;
}

extern "C" void kernel_launch(void* const* d_in, const int* in_sizes, int n_in,
                              void* d_out, int out_size, void* d_ws, size_t ws_size,
                              hipStream_t stream) {
    const float* X     = (const float*)d_in[0];
    const float* dist  = (const float*)d_in[1];
    const void*  nm    = d_in[2];   // non_missing_fix_X (bool)
    const void*  mkfit = d_in[3];   // mask_fit_X (bool)
    const int*   dmap  = (const int*)d_in[4];
    const void*  maskp = d_in[5];   // mask (bool)
    const int*   rmi   = (const int*)d_in[6];
    const float* fitX  = (const float*)d_in[7];
    float* out = (float*)d_out;

    // workspace layout
    u64*   wslists = (u64*)d_ws;                              // 16384*5*8 = 640 KB
    char*  base    = (char*)d_ws + (size_t)N_CHUNKS * 5 * 8;
    int*   wflag   = (int*)base;
    float* cmean   = (float*)(base + 4);
    float* partial = (float*)(base + 8);                      // 512 B
    unsigned char* inmiss = (unsigned char*)base + 520;       // NQ bytes
    unsigned char* pot8   = (unsigned char*)base + 520 + NQ;  // NT bytes, 4-aligned

    prep1_kernel<<<64, 256, 0, stream>>>(nm, mkfit, fitX, wflag, partial, inmiss, pot8);
    prep2_kernel<<<1, 256, 0, stream>>>(rmi, partial, cmean, inmiss);
    pass1_kernel<<<P1_BLOCKS, 256, 0, stream>>>(dist, pot8, wslists);
    pass2_kernel<<<(NQ + 255) / 256, 256, 0, stream>>>(X, wslists, maskp, mkfit,
                                                       fitX, dmap, wflag, cmean,
                                                       inmiss, pot8, out);
}

// Round 7
// 271.592 us; speedup vs baseline: 21.8508x; 21.8508x over previous
//
#include <hip/hip_runtime.h>
#include <math.h>

#define NQ 4096
#define NT 16384
#define DD 32
#define COLIDX 0
#define BIGF 1.0e10f
#define INFF __builtin_inff()

typedef unsigned long long u64;

// chunking: one block per 16 KB quarter-row
#define CHUNK_ELEMS 4096
#define CHUNK_VECS 1024               // float4s per chunk
#define CHUNKS_PER_ROW 4
#define N_CHUNKS (NQ * CHUNKS_PER_ROW)   // 16384

// ---------------------------------------------------------------------------
// bool-width helpers (unknown numpy bool storage: u8 vs i32)
// ---------------------------------------------------------------------------
__device__ __forceinline__ int boolat(const void* p, long long idx, int w32) {
    if (w32) return ((const int*)p)[idx] != 0;
    return ((const unsigned char*)p)[idx] != 0;
}

__device__ __forceinline__ int detect_w32(const void* nm, const void* mk,
                                          int tid, int* s_bad) {
    if (tid == 0) *s_bad = 0;
    __syncthreads();
    const unsigned char* nm8 = (const unsigned char*)nm;
    const unsigned char* mk8 = (const unsigned char*)mk;
    int bad = 0;
    for (int b = tid; b < 4096; b += 256)
        if ((int)nm8[b] + (int)mk8[b] != 1) bad = 1;
    if (bad) atomicOr(s_bad, 1);
    __syncthreads();
    return *s_bad ? 1 : 0;
}

// ---------------------------------------------------------------------------
// prep1: 64 blocks x 256 threads — pot8 pack, colmean partials, inmiss clear.
// ---------------------------------------------------------------------------
__global__ __launch_bounds__(256) void prep1_kernel(
    const void* __restrict__ nm, const void* __restrict__ mk,
    const float* __restrict__ fitX,
    int* __restrict__ wflag, float* __restrict__ partial,
    unsigned char* __restrict__ inmiss, unsigned char* __restrict__ pot8)
{
    __shared__ int s_bad;
    __shared__ float sc[256], sm[256];
    const int tid = threadIdx.x;
    const int w32 = detect_w32(nm, mk, tid, &s_bad);
    if (blockIdx.x == 0 && tid == 0) *wflag = w32;

    const int t = blockIdx.x * 256 + tid;          // 0..16383
    pot8[t] = (unsigned char)boolat(nm, (long long)t * DD + COLIDX, w32);

    float cs = 0.0f, ms = 0.0f;
    if (!boolat(mk, (long long)t * DD + COLIDX, w32)) {
        cs = fitX[(long long)t * DD + COLIDX];
        ms = 1.0f;
    }
    sc[tid] = cs; sm[tid] = ms;
    __syncthreads();
#pragma unroll
    for (int s = 128; s > 0; s >>= 1) {
        if (tid < s) { sc[tid] += sc[tid + s]; sm[tid] += sm[tid + s]; }
        __syncthreads();
    }
    if (tid == 0) { partial[blockIdx.x * 2] = sc[0]; partial[blockIdx.x * 2 + 1] = sm[0]; }

    if (t < NQ) inmiss[t] = 0;
}

__global__ __launch_bounds__(256) void prep2_kernel(
    const int* __restrict__ rmi, const float* __restrict__ partial,
    float* __restrict__ cmean, unsigned char* __restrict__ inmiss)
{
    const int tid = threadIdx.x;
    for (int i = tid; i < NQ; i += 256) {
        int r = rmi[i];
        if (r >= 0 && r < NQ) inmiss[r] = 1;
    }
    if (tid == 0) {
        float c = 0.0f, m = 0.0f;
        for (int b = 0; b < 64; ++b) { c += partial[2 * b]; m += partial[2 * b + 1]; }
        *cmean = c / (m > 0.0f ? m : 1.0f);
    }
}

// ---------------------------------------------------------------------------
// top-5 primitives
// ---------------------------------------------------------------------------
// f32/i32 branchless insert, strict < (per-thread ids ascend, so equal keys
// keep the earlier id). Proven 24-VGPR-class in round 4.
__device__ __forceinline__ void insert_scan(float key, int t, float v[5], int id[5]) {
    const bool c0 = key < v[0];
    const bool c1 = key < v[1];
    const bool c2 = key < v[2];
    const bool c3 = key < v[3];
    const bool c4 = key < v[4];
    v[4] = c4 ? (c3 ? v[3] : key) : v[4];  id[4] = c4 ? (c3 ? id[3] : t) : id[4];
    v[3] = c3 ? (c2 ? v[2] : key) : v[3];  id[3] = c3 ? (c2 ? id[2] : t) : id[3];
    v[2] = c2 ? (c1 ? v[1] : key) : v[2];  id[2] = c2 ? (c1 ? id[1] : t) : id[2];
    v[1] = c1 ? (c0 ? v[0] : key) : v[1];  id[1] = c1 ? (c0 ? id[0] : t) : id[1];
    v[0] = c0 ? key : v[0];                id[0] = c0 ? t : id[0];
}

// packed u64: (float_bits << 32) | col. Positive-float bit order == numeric
// order, so u64 asc == (key asc, col asc) == exact top_k tie-break.
__device__ __forceinline__ u64 u64min(u64 a, u64 b) { return (b < a) ? b : a; }

__device__ __forceinline__ void cas64(u64& x, u64& y) {
    const bool c = y < x;
    const u64 lo = c ? y : x;
    const u64 hi = c ? x : y;
    x = lo; y = hi;
}

// Merge two ascending sorted-5 lists, keep lowest 5, output sorted.
// Half-cleaner min(a_i, b_{4-i}) -> mountain; then pruned bitonic merge:
// d=4: cas(0,4); d=2: cas(1,3), cas(2,4); d=1: cas(1,2), cas(3,4).
// (Network fixed in round 6; verified on mountain permutations.)
__device__ __forceinline__ void merge_sorted5(u64 a[5], const u64 b[5]) {
    u64 m0 = u64min(a[0], b[4]);
    u64 m1 = u64min(a[1], b[3]);
    u64 m2 = u64min(a[2], b[2]);
    u64 m3 = u64min(a[3], b[1]);
    u64 m4 = u64min(a[4], b[0]);
    cas64(m0, m4);
    cas64(m1, m3); cas64(m2, m4);
    cas64(m1, m2); cas64(m3, m4);
    a[0] = m0; a[1] = m1; a[2] = m2; a[3] = m3; a[4] = m4;
}

__device__ __forceinline__ u64 shflx64(u64 x, int mask) {
    const int lo = __shfl_xor((int)(unsigned)x, mask, 64);
    const int hi = __shfl_xor((int)(unsigned)(x >> 32), mask, 64);
    return ((u64)(unsigned)hi << 32) | (u64)(unsigned)lo;
}

// insert into sorted u64 5-list (exact: packed keys are globally unique)
__device__ __forceinline__ void insert64(u64 k, u64 v[5]) {
    const bool c0 = k < v[0];
    const bool c1 = k < v[1];
    const bool c2 = k < v[2];
    const bool c3 = k < v[3];
    const bool c4 = k < v[4];
    v[4] = c4 ? (c3 ? v[3] : k) : v[4];
    v[3] = c3 ? (c2 ? v[2] : k) : v[3];
    v[2] = c2 ? (c1 ? v[1] : k) : v[2];
    v[1] = c1 ? (c0 ? v[0] : k) : v[1];
    v[0] = c0 ? k : v[0];
}

// ---------------------------------------------------------------------------
// Pass 1: ONE chunk (16 KB quarter-row) per block, no loop, no prefetch.
// blockIdx.x == chunkid; consecutive blocks read consecutive memory, so the
// in-flight working set is a dense contiguous slab (DRAM row-hit friendly).
// Minimal live set (~40 VGPR) — no spill (round-6 lesson: 17 GB scratch).
// ---------------------------------------------------------------------------
__global__ __launch_bounds__(256) void pass1_kernel(
    const float* __restrict__ dist,
    const unsigned char* __restrict__ pot8,
    u64* __restrict__ wslists)
{
    __shared__ u64 sv[3][5];
    const int tid = threadIdx.x;
    const int chunkid = blockIdx.x;
    const int sub = chunkid & (CHUNKS_PER_ROW - 1);

    const float4* dvec = (const float4*)dist + (long long)chunkid * CHUNK_VECS;
    const uchar4* pvec = (const uchar4*)pot8 + sub * (CHUNK_VECS);

    // 4 coalesced float4 + 4 uchar4 loads, batched (independent)
    const float4 c0 = dvec[0 * 256 + tid];
    const float4 c1 = dvec[1 * 256 + tid];
    const float4 c2 = dvec[2 * 256 + tid];
    const float4 c3 = dvec[3 * 256 + tid];
    const uchar4 q0 = pvec[0 * 256 + tid];
    const uchar4 q1 = pvec[1 * 256 + tid];
    const uchar4 q2 = pvec[2 * 256 + tid];
    const uchar4 q3 = pvec[3 * 256 + tid];

    float v[5]; int id[5];
#pragma unroll
    for (int k = 0; k < 5; ++k) { v[k] = INFF; id[k] = 0x7fffffff; }

    // key: pot ? (NaN ? BIGF : d) : +inf.  fminf(NaN, BIGF) == BIGF.
#define PROC(dc, qc, kk)                                                      \
    {                                                                         \
        const int cb = sub * CHUNK_ELEMS + ((kk) * 256 + tid) * 4;            \
        { const float key = (qc.x != 0) ? fminf(dc.x, BIGF) : INFF;           \
          insert_scan(key, cb + 0, v, id); }                                  \
        { const float key = (qc.y != 0) ? fminf(dc.y, BIGF) : INFF;           \
          insert_scan(key, cb + 1, v, id); }                                  \
        { const float key = (qc.z != 0) ? fminf(dc.z, BIGF) : INFF;           \
          insert_scan(key, cb + 2, v, id); }                                  \
        { const float key = (qc.w != 0) ? fminf(dc.w, BIGF) : INFF;           \
          insert_scan(key, cb + 3, v, id); }                                  \
    }
    PROC(c0, q0, 0)
    PROC(c1, q1, 1)
    PROC(c2, q2, 2)
    PROC(c3, q3, 3)
#undef PROC

    // pack to u64 (exact global order from here on)
    u64 vv[5];
#pragma unroll
    for (int k = 0; k < 5; ++k)
        vv[k] = ((u64)__float_as_uint(v[k]) << 32) | (u64)(unsigned)id[k];

    // 6-stage butterfly across the wave (all lanes converge)
#pragma unroll
    for (int mask = 1; mask <= 32; mask <<= 1) {
        u64 b[5];
#pragma unroll
        for (int k = 0; k < 5; ++k) b[k] = shflx64(vv[k], mask);
        merge_sorted5(vv, b);
    }

    // cross-wave via LDS; tid 0 finalizes
    const int wave = tid >> 6;
    if (wave > 0 && (tid & 63) == 0) {
#pragma unroll
        for (int k = 0; k < 5; ++k) sv[wave - 1][k] = vv[k];
    }
    __syncthreads();
    if (tid == 0) {
        u64 b[5];
#pragma unroll
        for (int w = 0; w < 3; ++w) {
            b[0] = sv[w][0]; b[1] = sv[w][1]; b[2] = sv[w][2];
            b[3] = sv[w][3]; b[4] = sv[w][4];
            merge_sorted5(vv, b);
        }
#pragma unroll
        for (int k = 0; k < 5; ++k)
            wslists[(long long)chunkid * 5 + k] = vv[k];
    }
}

// ---------------------------------------------------------------------------
// Pass 2: one thread per query row — merge 4 chunk-lists, epilogue, row copy.
// (Logic unchanged from round 6 — validated, absmax 0.)
// ---------------------------------------------------------------------------
__global__ __launch_bounds__(256) void pass2_kernel(
    const float* __restrict__ X,
    const u64* __restrict__ wslists,
    const void* __restrict__ maskp,
    const void* __restrict__ mkfitp,
    const float* __restrict__ fitX,
    const int* __restrict__ dmap,
    const int* __restrict__ wflagp,
    const float* __restrict__ cmeanp,
    const unsigned char* __restrict__ inmiss,
    const unsigned char* __restrict__ pot8,
    float* __restrict__ out)
{
    const int r = blockIdx.x * 256 + threadIdx.x;
    if (r >= NQ) return;

    // pass-through copy (cols 1..31); col 0 written below
#pragma unroll
    for (int c = 1; c < DD; ++c)
        out[(long long)r * DD + c] = X[(long long)r * DD + c];

    const int q = dmap[r];
    u64 v[5];
#pragma unroll
    for (int k = 0; k < 5; ++k) v[k] = 0xFFFFFFFFFFFFFFFFULL;
    const u64* lp = wslists + (long long)q * CHUNKS_PER_ROW * 5;
#pragma unroll
    for (int c = 0; c < CHUNKS_PER_ROW * 5; ++c) insert64(lp[c], v);

    const int w32 = *wflagp;
    const bool has_valid = (unsigned)(v[0] >> 32) < __float_as_uint(BIGF);
    const bool receiver =
        inmiss[r] && boolat(maskp, (long long)r * DD + COLIDX, w32);

    float val;
    if (!receiver) {
        val = X[(long long)r * DD + COLIDX];
    } else if (!has_valid) {
        val = *cmeanp;
    } else {
        float keyf[5]; bool ok[5]; int idxc[5];
#pragma unroll
        for (int k = 0; k < 5; ++k) {
            keyf[k] = __uint_as_float((unsigned)(v[k] >> 32));
            const unsigned id = (unsigned)(v[k] & 0xFFFFFFFFu);
            ok[k] = id < NT;
            idxc[k] = ok[k] ? (int)id : 0;
        }
        float dnr[5]; int mfv[5]; unsigned char vldb[5];
#pragma unroll
        for (int k = 0; k < 5; ++k)
            dnr[k] = fitX[(long long)idxc[k] * DD + COLIDX];
#pragma unroll
        for (int k = 0; k < 5; ++k)
            mfv[k] = boolat(mkfitp, (long long)idxc[k] * DD + COLIDX, w32);
#pragma unroll
        for (int k = 0; k < 5; ++k) vldb[k] = pot8[idxc[k]];

        float wk[5];
        bool infrow = false;
#pragma unroll
        for (int k = 0; k < 5; ++k) {
            const float dpot = (keyf[k] == BIGF) ? __builtin_nanf("") : keyf[k];
            const float t = 1.0f / dpot;       // 0->inf, inf->0, NaN->NaN
            wk[k] = ok[k] ? t : 0.0f;
            if (ok[k] && isinf(t)) infrow = true;
        }
        if (infrow) {
#pragma unroll
            for (int k = 0; k < 5; ++k) wk[k] = isinf(wk[k]) ? 1.0f : 0.0f;
        }
#pragma unroll
        for (int k = 0; k < 5; ++k) if (wk[k] != wk[k]) wk[k] = 0.0f;

        float wsum = 0.0f, vsum = 0.0f;
#pragma unroll
        for (int k = 0; k < 5; ++k) {
            const float dm = ok[k] ? (1.0f - (float)mfv[k]) : 0.0f;
            const float vl = ok[k] ? (float)vldb[k] : 0.0f;
            const float nw = dm * wk[k] * vl;
            wsum += nw;
            vsum += dnr[k] * nw;
        }
        const float div = (wsum == 0.0f) ? 1.0f : wsum;
        val = vsum / div;
    }
    out[(long long)r * DD + COLIDX] = val;
}

extern "C" void kernel_launch(void* const* d_in, const int* in_sizes, int n_in,
                              void* d_out, int out_size, void* d_ws, size_t ws_size,
                              hipStream_t stream) {
    const float* X     = (const float*)d_in[0];
    const float* dist  = (const float*)d_in[1];
    const void*  nm    = d_in[2];   // non_missing_fix_X (bool)
    const void*  mkfit = d_in[3];   // mask_fit_X (bool)
    const int*   dmap  = (const int*)d_in[4];
    const void*  maskp = d_in[5];   // mask (bool)
    const int*   rmi   = (const int*)d_in[6];
    const float* fitX  = (const float*)d_in[7];
    float* out = (float*)d_out;

    // workspace layout
    u64*   wslists = (u64*)d_ws;                              // 16384*5*8 = 640 KB
    char*  base    = (char*)d_ws + (size_t)N_CHUNKS * 5 * 8;
    int*   wflag   = (int*)base;
    float* cmean   = (float*)(base + 4);
    float* partial = (float*)(base + 8);                      // 512 B
    unsigned char* inmiss = (unsigned char*)base + 520;       // NQ bytes
    unsigned char* pot8   = (unsigned char*)base + 520 + NQ;  // NT bytes, 4-aligned

    prep1_kernel<<<64, 256, 0, stream>>>(nm, mkfit, fitX, wflag, partial, inmiss, pot8);
    prep2_kernel<<<1, 256, 0, stream>>>(rmi, partial, cmean, inmiss);
    pass1_kernel<<<N_CHUNKS, 256, 0, stream>>>(dist, pot8, wslists);
    pass2_kernel<<<(NQ + 255) / 256, 256, 0, stream>>>(X, wslists, maskp, mkfit,
                                                       fitX, dmap, wflag, cmean,
                                                       inmiss, pot8, out);
}

// Round 8
// 87.958 us; speedup vs baseline: 67.4698x; 3.0878x over previous
//
#include <hip/hip_runtime.h>
#include <math.h>

#define NQ 4096
#define NT 16384
#define DD 32
#define COLIDX 0
#define BIGF 1.0e10f
#define INFF __builtin_inff()

typedef unsigned long long u64;

// pass1: one block per row; 64 elems/thread in 4 batches of 4 float4-groups
#define ROW_VECS (NT / 4)            // 4096 float4 per row
#define NBATCH 4
#define GPB 4                        // float4-groups per batch

// ---------------------------------------------------------------------------
// bool-width helpers (unknown numpy bool storage: u8 vs i32)
// ---------------------------------------------------------------------------
__device__ __forceinline__ int boolat(const void* p, long long idx, int w32) {
    if (w32) return ((const int*)p)[idx] != 0;
    return ((const unsigned char*)p)[idx] != 0;
}

__device__ __forceinline__ int detect_w32(const void* nm, const void* mk,
                                          int tid, int* s_bad) {
    if (tid == 0) *s_bad = 0;
    __syncthreads();
    const unsigned char* nm8 = (const unsigned char*)nm;
    const unsigned char* mk8 = (const unsigned char*)mk;
    int bad = 0;
    for (int b = tid; b < 4096; b += 256)
        if ((int)nm8[b] + (int)mk8[b] != 1) bad = 1;
    if (bad) atomicOr(s_bad, 1);
    __syncthreads();
    return *s_bad ? 1 : 0;
}

// ---------------------------------------------------------------------------
// prep1: 64 blocks x 256 threads — pot8 pack, colmean partials, inmiss clear.
// ---------------------------------------------------------------------------
__global__ __launch_bounds__(256) void prep1_kernel(
    const void* __restrict__ nm, const void* __restrict__ mk,
    const float* __restrict__ fitX,
    int* __restrict__ wflag, float* __restrict__ partial,
    unsigned char* __restrict__ inmiss, unsigned char* __restrict__ pot8)
{
    __shared__ int s_bad;
    __shared__ float sc[256], sm[256];
    const int tid = threadIdx.x;
    const int w32 = detect_w32(nm, mk, tid, &s_bad);
    if (blockIdx.x == 0 && tid == 0) *wflag = w32;

    const int t = blockIdx.x * 256 + tid;          // 0..16383
    pot8[t] = (unsigned char)boolat(nm, (long long)t * DD + COLIDX, w32);

    float cs = 0.0f, ms = 0.0f;
    if (!boolat(mk, (long long)t * DD + COLIDX, w32)) {
        cs = fitX[(long long)t * DD + COLIDX];
        ms = 1.0f;
    }
    sc[tid] = cs; sm[tid] = ms;
    __syncthreads();
#pragma unroll
    for (int s = 128; s > 0; s >>= 1) {
        if (tid < s) { sc[tid] += sc[tid + s]; sm[tid] += sm[tid + s]; }
        __syncthreads();
    }
    if (tid == 0) { partial[blockIdx.x * 2] = sc[0]; partial[blockIdx.x * 2 + 1] = sm[0]; }

    if (t < NQ) inmiss[t] = 0;
}

__global__ __launch_bounds__(256) void prep2_kernel(
    const int* __restrict__ rmi, const float* __restrict__ partial,
    float* __restrict__ cmean, unsigned char* __restrict__ inmiss)
{
    const int tid = threadIdx.x;
    for (int i = tid; i < NQ; i += 256) {
        int r = rmi[i];
        if (r >= 0 && r < NQ) inmiss[r] = 1;
    }
    if (tid == 0) {
        float c = 0.0f, m = 0.0f;
        for (int b = 0; b < 64; ++b) { c += partial[2 * b]; m += partial[2 * b + 1]; }
        *cmean = c / (m > 0.0f ? m : 1.0f);
    }
}

// ---------------------------------------------------------------------------
// packed-u64 primitives. key64 = (float_bits << 32) | idx. Positive-float
// bit order == numeric order, so u64 asc == (key asc, idx asc) == exact
// jax.lax.top_k tie-break. All keys globally UNIQUE (idx differs) -> total
// order, sorting networks need no stability care.
// ---------------------------------------------------------------------------
__device__ __forceinline__ u64 u64min(u64 a, u64 b) { return (b < a) ? b : a; }

__device__ __forceinline__ void cas64(u64& x, u64& y) {
    const bool c = y < x;
    const u64 lo = c ? y : x;
    const u64 hi = c ? x : y;
    x = lo; y = hi;
}

// key: pot ? (NaN ? BIGF : d) : +inf.  fminf(NaN, BIGF) == BIGF (v_min_f32
// returns the non-NaN operand). Validated absmax=0 in rounds 6-7.
__device__ __forceinline__ u64 mkkey(float d, unsigned char p, unsigned idx) {
    const float key = (p != 0) ? fminf(d, BIGF) : INFF;
    return ((u64)__float_as_uint(key) << 32) | (u64)idx;
}

// Merge two ascending sorted-5 lists, keep lowest 5, output sorted.
// Half-cleaner min(a_i, b_{4-i}) -> mountain (valley impossible: falling
// start needs b3<a0, rising end needs b0>a3, but b0<=b3 -> contradiction);
// then pruned bitonic cleanup: cas(0,4),(1,3),(2,4),(1,2),(3,4).
// Verified in rounds 6-7 (absmax=0).
__device__ __forceinline__ void merge_sorted5(u64 a[5], const u64 b[5]) {
    u64 m0 = u64min(a[0], b[4]);
    u64 m1 = u64min(a[1], b[3]);
    u64 m2 = u64min(a[2], b[2]);
    u64 m3 = u64min(a[3], b[1]);
    u64 m4 = u64min(a[4], b[0]);
    cas64(m0, m4);
    cas64(m1, m3); cas64(m2, m4);
    cas64(m1, m2); cas64(m3, m4);
    a[0] = m0; a[1] = m1; a[2] = m2; a[3] = m3; a[4] = m4;
}

__device__ __forceinline__ u64 shflx64(u64 x, int mask) {
    const int lo = __shfl_xor((int)(unsigned)x, mask, 64);
    const int hi = __shfl_xor((int)(unsigned)(x >> 32), mask, 64);
    return ((u64)(unsigned)hi << 32) | (u64)(unsigned)lo;
}

// ---------------------------------------------------------------------------
// Pass 1: ONE row per block (4096 blocks). Each thread scans 64 elements in
// 4 batches of 4 float4-groups (small live set -> no spill; round-6 lesson).
// Per group: sort4 network on packed u64 (5 CAS), then half-cleaner merge
// into the running sorted-5 with MAX pad:
//   b' = [s0,s1,s2,s3,MAX]: m0=a0, m1=min(a1,s3), m2=min(a2,s2),
//   m3=min(a3,s1), m4=min(a4,s0)  -> mountain -> verified cleanup.
// ~20 VALU/elem vs ~30 for per-element insert; butterfly amortized 4x.
// ---------------------------------------------------------------------------
__global__ __launch_bounds__(256) void pass1_kernel(
    const float* __restrict__ dist,
    const unsigned char* __restrict__ pot8,
    u64* __restrict__ wslists)
{
    __shared__ u64 sv[3][5];
    const int tid = threadIdx.x;
    const int row = blockIdx.x;

    const float4* dvec = (const float4*)dist + (long long)row * ROW_VECS;
    const uchar4* pvec = (const uchar4*)pot8;

    u64 v[5];
#pragma unroll
    for (int k = 0; k < 5; ++k) v[k] = 0xFFFFFFFFFFFFFFFFULL;

#pragma unroll 1
    for (int half = 0; half < NBATCH; ++half) {
        float4 dd[GPB]; uchar4 pp[GPB];
#pragma unroll
        for (int g = 0; g < GPB; ++g) {
            const int vecidx = (half * GPB + g) * 256 + tid;
            dd[g] = dvec[vecidx];
            pp[g] = pvec[vecidx];
        }
#pragma unroll
        for (int g = 0; g < GPB; ++g) {
            const unsigned base = (unsigned)(((half * GPB + g) * 256 + tid) * 4);
            u64 s0 = mkkey(dd[g].x, pp[g].x, base + 0);
            u64 s1 = mkkey(dd[g].y, pp[g].y, base + 1);
            u64 s2 = mkkey(dd[g].z, pp[g].z, base + 2);
            u64 s3 = mkkey(dd[g].w, pp[g].w, base + 3);
            // sort4: optimal network (0,1)(2,3)(0,2)(1,3)(1,2)
            cas64(s0, s1); cas64(s2, s3);
            cas64(s0, s2); cas64(s1, s3);
            cas64(s1, s2);
            // merge sorted-4 into running sorted-5 (b4 = MAX pad -> m0 = v[0])
            u64 m0 = v[0];
            u64 m1 = u64min(v[1], s3);
            u64 m2 = u64min(v[2], s2);
            u64 m3 = u64min(v[3], s1);
            u64 m4 = u64min(v[4], s0);
            cas64(m0, m4);
            cas64(m1, m3); cas64(m2, m4);
            cas64(m1, m2); cas64(m3, m4);
            v[0] = m0; v[1] = m1; v[2] = m2; v[3] = m3; v[4] = m4;
        }
    }

    // 6-stage butterfly across the wave (verified)
#pragma unroll
    for (int mask = 1; mask <= 32; mask <<= 1) {
        u64 b[5];
#pragma unroll
        for (int k = 0; k < 5; ++k) b[k] = shflx64(v[k], mask);
        merge_sorted5(v, b);
    }

    // cross-wave via LDS; tid 0 finalizes
    const int wave = tid >> 6;
    if (wave > 0 && (tid & 63) == 0) {
#pragma unroll
        for (int k = 0; k < 5; ++k) sv[wave - 1][k] = v[k];
    }
    __syncthreads();
    if (tid == 0) {
        u64 b[5];
#pragma unroll
        for (int w = 0; w < 3; ++w) {
            b[0] = sv[w][0]; b[1] = sv[w][1]; b[2] = sv[w][2];
            b[3] = sv[w][3]; b[4] = sv[w][4];
            merge_sorted5(v, b);
        }
#pragma unroll
        for (int k = 0; k < 5; ++k)
            wslists[(long long)row * 5 + k] = v[k];
    }
}

// ---------------------------------------------------------------------------
// Pass 2: one thread per query row — load the row's sorted 5-list, epilogue,
// row copy. (Epilogue logic validated rounds 6-7, absmax 0.)
// ---------------------------------------------------------------------------
__global__ __launch_bounds__(256) void pass2_kernel(
    const float* __restrict__ X,
    const u64* __restrict__ wslists,
    const void* __restrict__ maskp,
    const void* __restrict__ mkfitp,
    const float* __restrict__ fitX,
    const int* __restrict__ dmap,
    const int* __restrict__ wflagp,
    const float* __restrict__ cmeanp,
    const unsigned char* __restrict__ inmiss,
    const unsigned char* __restrict__ pot8,
    float* __restrict__ out)
{
    const int r = blockIdx.x * 256 + threadIdx.x;
    if (r >= NQ) return;

    // pass-through copy (cols 1..31); col 0 written below
#pragma unroll
    for (int c = 1; c < DD; ++c)
        out[(long long)r * DD + c] = X[(long long)r * DD + c];

    const int q = dmap[r];
    u64 v[5];
    const u64* lp = wslists + (long long)q * 5;
#pragma unroll
    for (int k = 0; k < 5; ++k) v[k] = lp[k];

    const int w32 = *wflagp;
    const bool has_valid = (unsigned)(v[0] >> 32) < __float_as_uint(BIGF);
    const bool receiver =
        inmiss[r] && boolat(maskp, (long long)r * DD + COLIDX, w32);

    float val;
    if (!receiver) {
        val = X[(long long)r * DD + COLIDX];
    } else if (!has_valid) {
        val = *cmeanp;
    } else {
        float keyf[5]; bool ok[5]; int idxc[5];
#pragma unroll
        for (int k = 0; k < 5; ++k) {
            keyf[k] = __uint_as_float((unsigned)(v[k] >> 32));
            const unsigned id = (unsigned)(v[k] & 0xFFFFFFFFu);
            ok[k] = id < NT;
            idxc[k] = ok[k] ? (int)id : 0;
        }
        float dnr[5]; int mfv[5]; unsigned char vldb[5];
#pragma unroll
        for (int k = 0; k < 5; ++k)
            dnr[k] = fitX[(long long)idxc[k] * DD + COLIDX];
#pragma unroll
        for (int k = 0; k < 5; ++k)
            mfv[k] = boolat(mkfitp, (long long)idxc[k] * DD + COLIDX, w32);
#pragma unroll
        for (int k = 0; k < 5; ++k) vldb[k] = pot8[idxc[k]];

        float wk[5];
        bool infrow = false;
#pragma unroll
        for (int k = 0; k < 5; ++k) {
            const float dpot = (keyf[k] == BIGF) ? __builtin_nanf("") : keyf[k];
            const float t = 1.0f / dpot;       // 0->inf, inf->0, NaN->NaN
            wk[k] = ok[k] ? t : 0.0f;
            if (ok[k] && isinf(t)) infrow = true;
        }
        if (infrow) {
#pragma unroll
            for (int k = 0; k < 5; ++k) wk[k] = isinf(wk[k]) ? 1.0f : 0.0f;
        }
#pragma unroll
        for (int k = 0; k < 5; ++k) if (wk[k] != wk[k]) wk[k] = 0.0f;

        float wsum = 0.0f, vsum = 0.0f;
#pragma unroll
        for (int k = 0; k < 5; ++k) {
            const float dm = ok[k] ? (1.0f - (float)mfv[k]) : 0.0f;
            const float vl = ok[k] ? (float)vldb[k] : 0.0f;
            const float nw = dm * wk[k] * vl;
            wsum += nw;
            vsum += dnr[k] * nw;
        }
        const float div = (wsum == 0.0f) ? 1.0f : wsum;
        val = vsum / div;
    }
    out[(long long)r * DD + COLIDX] = val;
}

extern "C" void kernel_launch(void* const* d_in, const int* in_sizes, int n_in,
                              void* d_out, int out_size, void* d_ws, size_t ws_size,
                              hipStream_t stream) {
    const float* X     = (const float*)d_in[0];
    const float* dist  = (const float*)d_in[1];
    const void*  nm    = d_in[2];   // non_missing_fix_X (bool)
    const void*  mkfit = d_in[3];   // mask_fit_X (bool)
    const int*   dmap  = (const int*)d_in[4];
    const void*  maskp = d_in[5];   // mask (bool)
    const int*   rmi   = (const int*)d_in[6];
    const float* fitX  = (const float*)d_in[7];
    float* out = (float*)d_out;

    // workspace layout
    u64*   wslists = (u64*)d_ws;                              // 4096*5*8 = 160 KB
    char*  base    = (char*)d_ws + (size_t)NQ * 5 * 8;
    int*   wflag   = (int*)base;
    float* cmean   = (float*)(base + 4);
    float* partial = (float*)(base + 8);                      // 512 B
    unsigned char* inmiss = (unsigned char*)base + 520;       // NQ bytes
    unsigned char* pot8   = (unsigned char*)base + 520 + NQ;  // NT bytes, 4-aligned

    prep1_kernel<<<64, 256, 0, stream>>>(nm, mkfit, fitX, wflag, partial, inmiss, pot8);
    prep2_kernel<<<1, 256, 0, stream>>>(rmi, partial, cmean, inmiss);
    pass1_kernel<<<NQ, 256, 0, stream>>>(dist, pot8, wslists);
    pass2_kernel<<<(NQ + 255) / 256, 256, 0, stream>>>(X, wslists, maskp, mkfit,
                                                       fitX, dmap, wflag, cmean,
                                                       inmiss, pot8, out);
}